// Round 1
// baseline (211.670 us; speedup 1.0000x reference)
//
#include <hip/hip_runtime.h>

#define SB 4096
#define BB 16
#define CC 512

struct Small {
  float tailpart[BB * 16];
  int   fl_old[BB];
  int   fl_new[BB];
  float scale[BB];
  int   T0;
};

// K0: detect mask dtype (uint8 bools vs int32) and canonicalize to uint8.
__global__ void k_mask_canon(const unsigned* mask_in, unsigned char* mask8) {
  __shared__ int s_flag;
  if (threadIdx.x == 0) s_flag = 0;
  __syncthreads();
  unsigned bad = 0;
  // First 16384 words are safe to read under either interpretation
  // (uint8: 65536 bytes total; int32: 262144 bytes total).
  for (int i = threadIdx.x; i < 16384; i += 256) {
    unsigned v = mask_in[i];
    bad |= (v > 1u) ? 1u : 0u;
  }
  if (bad) atomicOr(&s_flag, 1);
  __syncthreads();
  if (s_flag) {
    const unsigned char* mb = (const unsigned char*)mask_in;
    for (int i = threadIdx.x; i < BB * SB; i += 256) mask8[i] = mb[i] ? 1 : 0;
  } else {
    const int* mi = (const int*)mask_in;
    for (int i = threadIdx.x; i < BB * SB; i += 256) mask8[i] = mi[i] ? 1 : 0;
  }
}

// K1: exact sequential (left-fold) float32 cumsum per batch; also feat_len and T0.
__global__ void k_scan(const float* __restrict__ alphas,
                       const unsigned char* __restrict__ mask8,
                       float* __restrict__ csum, Small* sm) {
  int b = threadIdx.x; // one lane per batch, lanes 16..63 idle
  float c = 0.f;
  if (b < BB) {
    const float* ab = alphas + b * SB;
    const unsigned char* mb = mask8 + b * SB;
    float* cb = csum + b * SB;
    for (int i0 = 0; i0 < SB; i0 += 16) {
      float4 a0 = *(const float4*)(ab + i0);
      float4 a1 = *(const float4*)(ab + i0 + 4);
      float4 a2 = *(const float4*)(ab + i0 + 8);
      float4 a3 = *(const float4*)(ab + i0 + 12);
      uint4 mv = *(const uint4*)(mb + i0);
      float av[16] = {a0.x, a0.y, a0.z, a0.w, a1.x, a1.y, a1.z, a1.w,
                      a2.x, a2.y, a2.z, a2.w, a3.x, a3.y, a3.z, a3.w};
      unsigned mw[4] = {mv.x, mv.y, mv.z, mv.w};
#pragma unroll
      for (int k = 0; k < 16; ++k) {
        unsigned mbyte = (mw[k >> 2] >> ((k & 3) * 8)) & 0xFFu;
        float a = mbyte ? 0.f : av[k];
        c += a;                // strict sequential association
        cb[i0 + k] = c;
      }
    }
  }
  int fl = (b < BB) ? (int)floorf(c) : 0;
  int mx = fl;
  for (int off = 32; off; off >>= 1) mx = max(mx, __shfl_down(mx, off));
  mx = __shfl(mx, 0);
  if (b < BB) sm->fl_old[b] = fl;
  if (b == 0) sm->T0 = mx;
}

// K3: per-element indices/weights + deterministic tail partials.
__global__ void k_weights(const float* __restrict__ alphas,
                          const unsigned char* __restrict__ mask8,
                          const float* __restrict__ csum,
                          int* __restrict__ ridx, float* __restrict__ rw,
                          float* __restrict__ lw, Small* sm) {
  int gid = blockIdx.x * 256 + threadIdx.x;
  int b = gid >> 12;
  int i = gid & (SB - 1);
  int T0 = sm->T0;
  float cs = csum[gid];
  int r = min((int)rintf(cs), T0);
  int p = 0;
  if (i) p = min((int)rintf(csum[gid - 1]), T0);
  int fire = r - p;
  float rwv = (fire > 0) ? (cs - (float)r) : 0.f;
  float am = mask8[gid] ? 0.f : alphas[gid];
  int extra = fire - 1; if (extra < 0) extra = 0;
  float lwv = (am - rwv) - (float)extra; // BETA = 1
  ridx[gid] = r; rw[gid] = rwv; lw[gid] = lwv;
  int fl = sm->fl_old[b];
  float tc = ((r == fl) ? rwv : 0.f) + ((p == fl) ? lwv : 0.f);
  __shared__ float red[4];
  for (int off = 32; off; off >>= 1) tc += __shfl_down(tc, off);
  int wid = threadIdx.x >> 6;
  if ((threadIdx.x & 63) == 0) red[wid] = tc;
  __syncthreads();
  if (threadIdx.x == 0) {
    float t = red[0] + red[1] + red[2] + red[3];
    sm->tailpart[b * 16 + (blockIdx.x & 15)] = t;
  }
}

// K4: tail sums (deterministic order), extend decision, scales, feat_lengths out.
__global__ void k_finalize(Small* sm, float* __restrict__ out1) {
  int b = threadIdx.x;
  if (b < BB) {
    float t = 0.f;
    for (int j = 0; j < 16; ++j) t += sm->tailpart[b * 16 + j];
    int e = (t >= 0.5f) ? 1 : 0;
    sm->scale[b] = e ? (1.0f / t) : 1.0f;
    int fln = sm->fl_old[b] + e;
    sm->fl_new[b] = fln;
    out1[b] = (float)max(fln, 1);
  }
}

// K5: gather per output row (b, t).
__global__ void __launch_bounds__(128)
k_gather(const float* __restrict__ src, const float* __restrict__ rw,
         const float* __restrict__ lw, const int* __restrict__ ridx,
         const Small* __restrict__ sm, float* __restrict__ out, int T) {
  int t = blockIdx.x;
  int b = blockIdx.y;
  int tid = threadIdx.x;
  float4* orow = (float4*)(out + ((size_t)(b * T + t)) * CC) + tid;
  int fln = sm->fl_new[b];
  if (t >= fln) { *orow = make_float4(0.f, 0.f, 0.f, 0.f); return; }
  int flo = sm->fl_old[b];
  float m = (t < flo) ? 1.0f : sm->scale[b];
  const int* R = ridx + b * SB;
  int lo = 0, hi = SB;
  while (lo < hi) { int mid = (lo + hi) >> 1; if (R[mid] < t) lo = mid + 1; else hi = mid; }
  int lo2 = lo, hi2 = SB;
  while (lo2 < hi2) { int mid = (lo2 + hi2) >> 1; if (R[mid] < t + 1) lo2 = mid + 1; else hi2 = mid; }
  int iend = min(lo2, SB - 1);
  const float* srcb = src + (size_t)b * SB * CC;
  int base = b * SB;
  float4 acc = make_float4(0.f, 0.f, 0.f, 0.f);
  for (int i = lo; i <= iend; ++i) {
    int r = R[i];
    int l = i ? R[i - 1] : 0;
    float w = 0.f;
    if (r == t) w += rw[base + i];
    if (l == t) w += lw[base + i];
    if (r > l + 1 && t > l && t < r) w += 1.0f; // extra fires (BETA=1), clip never binds since r<=T0
    if (w != 0.f) {
      float4 s = ((const float4*)(srcb + (size_t)i * CC))[tid];
      acc.x = fmaf(w, s.x, acc.x);
      acc.y = fmaf(w, s.y, acc.y);
      acc.z = fmaf(w, s.z, acc.z);
      acc.w = fmaf(w, s.w, acc.w);
    }
  }
  acc.x *= m; acc.y *= m; acc.z *= m; acc.w *= m;
  *orow = acc;
}

extern "C" void kernel_launch(void* const* d_in, const int* in_sizes, int n_in,
                              void* d_out, int out_size, void* d_ws, size_t ws_size,
                              hipStream_t stream) {
  const float* src = (const float*)d_in[0];
  const unsigned* mask = (const unsigned*)d_in[1];
  const float* alphas = (const float*)d_in[2];
  float* out = (float*)d_out;
  char* ws = (char*)d_ws;

  float* csum          = (float*)(ws + 0);
  int* ridx            = (int*)(ws + 262144);
  float* rw            = (float*)(ws + 524288);
  float* lw            = (float*)(ws + 786432);
  unsigned char* mask8 = (unsigned char*)(ws + 1048576);
  Small* sm            = (Small*)(ws + 1114112);

  int T = (out_size - BB) / (BB * CC);

  k_mask_canon<<<1, 256, 0, stream>>>(mask, mask8);
  k_scan<<<1, 64, 0, stream>>>(alphas, mask8, csum, sm);
  k_weights<<<256, 256, 0, stream>>>(alphas, mask8, csum, ridx, rw, lw, sm);
  k_finalize<<<1, 64, 0, stream>>>(sm, out + (size_t)BB * T * CC);
  dim3 g(T, BB);
  k_gather<<<g, 128, 0, stream>>>(src, rw, lw, ridx, sm, out, T);
}

// Round 2
// 59.336 us; speedup vs baseline: 3.5673x; 3.5673x over previous
//
#include <hip/hip_runtime.h>

#define SB 4096
#define BB 16
#define CC 512

struct Small {
  float tailpart[BB * 16];
  int   fl_old[BB];
  int   fl_new[BB];
  float scale[BB];
  int   T0;
  int   flag_u8;
};

// K0: detect mask dtype (uint8 bools vs int32), init Small.
// Only reads first 16384 words (= 64KB), safe under either interpretation.
__global__ void k_detect(const unsigned* __restrict__ mask_in, Small* sm) {
  __shared__ int s_flag;
  if (threadIdx.x == 0) s_flag = 0;
  __syncthreads();
  unsigned bad = 0;
  for (int i = threadIdx.x; i < 16384; i += 1024) {
    unsigned v = mask_in[i];
    bad |= (v > 1u) ? 1u : 0u;
  }
  if (bad) atomicOr(&s_flag, 1);
  __syncthreads();
  if (threadIdx.x == 0) {
    sm->flag_u8 = s_flag;   // nonzero => mask stored as packed uint8 bools
    sm->T0 = 0;
  }
}

// K1: parallel per-batch cumsum. One block (256 thr) per batch; each thread
// folds 16 contiguous elements, tree-scan across threads, re-fold with offset.
__global__ void __launch_bounds__(256)
k_scan_par(const float* __restrict__ alphas, const void* __restrict__ mask,
           float* __restrict__ csum, Small* sm) {
  int b = blockIdx.x;
  int t = threadIdx.x;
  int lane = t & 63, wid = t >> 6;
  int base = t * 16;
  const float* ab = alphas + b * SB + base;
  float av[16];
#pragma unroll
  for (int k = 0; k < 16; k += 4) {
    float4 v = *(const float4*)(ab + k);
    av[k] = v.x; av[k + 1] = v.y; av[k + 2] = v.z; av[k + 3] = v.w;
  }
  if (sm->flag_u8) {
    const unsigned char* mb = (const unsigned char*)mask + b * SB + base;
    uint4 mv = *(const uint4*)mb;
    unsigned mw[4] = {mv.x, mv.y, mv.z, mv.w};
#pragma unroll
    for (int k = 0; k < 16; ++k)
      if ((mw[k >> 2] >> ((k & 3) * 8)) & 0xFFu) av[k] = 0.f;
  } else {
    const int* mi = (const int*)mask + b * SB + base;
#pragma unroll
    for (int k = 0; k < 16; ++k)
      if (mi[k]) av[k] = 0.f;
  }
  float s = 0.f;
#pragma unroll
  for (int k = 0; k < 16; ++k) s += av[k];
  // inclusive wave scan of thread sums
  float si = s;
#pragma unroll
  for (int off = 1; off < 64; off <<= 1) {
    float v = __shfl_up(si, off);
    if (lane >= off) si += v;
  }
  __shared__ float wsum[4];
  if (lane == 63) wsum[wid] = si;
  __syncthreads();
  float woff = 0.f;
  for (int w = 0; w < wid; ++w) woff += wsum[w];
  float excl = woff + (si - s);  // exclusive prefix for this thread
  float c = excl;
  float* cb = csum + b * SB + base;
#pragma unroll
  for (int k = 0; k < 16; ++k) { c += av[k]; cb[k] = c; }
  if (t == 255) {
    float total = woff + si;
    int fl = (int)floorf(total);
    sm->fl_old[b] = fl;
    atomicMax(&sm->T0, fl);
  }
}

// K2: per-element indices/weights + deterministic tail partials.
__global__ void k_weights(const float* __restrict__ alphas,
                          const void* __restrict__ mask,
                          const float* __restrict__ csum,
                          int* __restrict__ ridx, float* __restrict__ rw,
                          float* __restrict__ lw, Small* sm) {
  int gid = blockIdx.x * 256 + threadIdx.x;
  int b = gid >> 12;
  int T0 = sm->T0;
  float cs = csum[gid];
  int r = min((int)rintf(cs), T0);
  int p = 0;
  if (gid & (SB - 1)) p = min((int)rintf(csum[gid - 1]), T0);
  int fire = r - p;
  float rwv = (fire > 0) ? (cs - (float)r) : 0.f;
  unsigned m;
  if (sm->flag_u8) m = ((const unsigned char*)mask)[gid];
  else             m = ((const int*)mask)[gid];
  float am = m ? 0.f : alphas[gid];
  int extra = fire - 1; if (extra < 0) extra = 0;
  float lwv = (am - rwv) - (float)extra; // BETA = 1
  ridx[gid] = r; rw[gid] = rwv; lw[gid] = lwv;
  int fl = sm->fl_old[b];
  float tc = ((r == fl) ? rwv : 0.f) + ((p == fl) ? lwv : 0.f);
  __shared__ float red[4];
  for (int off = 32; off; off >>= 1) tc += __shfl_down(tc, off);
  int wid = threadIdx.x >> 6;
  if ((threadIdx.x & 63) == 0) red[wid] = tc;
  __syncthreads();
  if (threadIdx.x == 0) {
    float t = red[0] + red[1] + red[2] + red[3];
    sm->tailpart[b * 16 + (blockIdx.x & 15)] = t;
  }
}

// K3: tail sums (deterministic order), extend decision, scales, feat_lengths out.
__global__ void k_finalize(Small* sm, float* __restrict__ out1) {
  int b = threadIdx.x;
  if (b < BB) {
    float t = 0.f;
    for (int j = 0; j < 16; ++j) t += sm->tailpart[b * 16 + j];
    int e = (t >= 0.5f) ? 1 : 0;
    sm->scale[b] = e ? (1.0f / t) : 1.0f;
    int fln = sm->fl_old[b] + e;
    sm->fl_new[b] = fln;
    out1[b] = (float)max(fln, 1);
  }
}

// K4: gather per output row (b, t).
__global__ void __launch_bounds__(128)
k_gather(const float* __restrict__ src, const float* __restrict__ rw,
         const float* __restrict__ lw, const int* __restrict__ ridx,
         const Small* __restrict__ sm, float* __restrict__ out, int T) {
  int t = blockIdx.x;
  int b = blockIdx.y;
  int tid = threadIdx.x;
  float4* orow = (float4*)(out + ((size_t)(b * T + t)) * CC) + tid;
  int fln = sm->fl_new[b];
  if (t >= fln) { *orow = make_float4(0.f, 0.f, 0.f, 0.f); return; }
  int flo = sm->fl_old[b];
  float m = (t < flo) ? 1.0f : sm->scale[b];
  const int* R = ridx + b * SB;
  int lo = 0, hi = SB;
  while (lo < hi) { int mid = (lo + hi) >> 1; if (R[mid] < t) lo = mid + 1; else hi = mid; }
  int lo2 = lo, hi2 = SB;
  while (lo2 < hi2) { int mid = (lo2 + hi2) >> 1; if (R[mid] < t + 1) lo2 = mid + 1; else hi2 = mid; }
  int iend = min(lo2, SB - 1);
  const float* srcb = src + (size_t)b * SB * CC;
  int base = b * SB;
  float4 acc = make_float4(0.f, 0.f, 0.f, 0.f);
  for (int i = lo; i <= iend; ++i) {
    int r = R[i];
    int l = i ? R[i - 1] : 0;
    float w = 0.f;
    if (r == t) w += rw[base + i];
    if (l == t) w += lw[base + i];
    if (r > l + 1 && t > l && t < r) w += 1.0f; // extra fires (BETA=1)
    if (w != 0.f) {
      float4 s = ((const float4*)(srcb + (size_t)i * CC))[tid];
      acc.x = fmaf(w, s.x, acc.x);
      acc.y = fmaf(w, s.y, acc.y);
      acc.z = fmaf(w, s.z, acc.z);
      acc.w = fmaf(w, s.w, acc.w);
    }
  }
  acc.x *= m; acc.y *= m; acc.z *= m; acc.w *= m;
  *orow = acc;
}

extern "C" void kernel_launch(void* const* d_in, const int* in_sizes, int n_in,
                              void* d_out, int out_size, void* d_ws, size_t ws_size,
                              hipStream_t stream) {
  const float* src = (const float*)d_in[0];
  const unsigned* mask = (const unsigned*)d_in[1];
  const float* alphas = (const float*)d_in[2];
  float* out = (float*)d_out;
  char* ws = (char*)d_ws;

  float* csum = (float*)(ws + 0);
  int* ridx   = (int*)(ws + 262144);
  float* rw   = (float*)(ws + 524288);
  float* lw   = (float*)(ws + 786432);
  Small* sm   = (Small*)(ws + 1048576);

  int T = (out_size - BB) / (BB * CC);

  k_detect<<<1, 1024, 0, stream>>>(mask, sm);
  k_scan_par<<<BB, 256, 0, stream>>>(alphas, mask, csum, sm);
  k_weights<<<256, 256, 0, stream>>>(alphas, mask, csum, ridx, rw, lw, sm);
  k_finalize<<<1, 64, 0, stream>>>(sm, out + (size_t)BB * T * CC);
  dim3 g(T, BB);
  k_gather<<<g, 128, 0, stream>>>(src, rw, lw, ridx, sm, out, T);
}